// Round 1
// baseline (382.419 us; speedup 1.0000x reference)
//
#include <hip/hip_runtime.h>

// NAVAR dims (fixed by the problem)
#define T_LEN   2048
#define BATCH   8
#define HIDDEN  16
#define KSZ     4
#define NVAR    12
#define NGROUPS 96      // ND*NS*NV = 2*4*12
#define TILE_OUT 232    // outputs per block tile
#define BUF     256     // TILE_OUT + HALO
#define HALO    24      // 3*(1+1+2+4) receptive-field halo
#define NTILES  9       // ceil(2048/232)

// prediction[b,d,s,v,t] = biases[d,s,v]  (init before atomic accumulation)
__global__ __launch_bounds__(256) void navar_init_pred(
        const float* __restrict__ biases, float* __restrict__ pred) {
    int e = blockIdx.x * 256 + threadIdx.x;   // grid sized exactly
    pred[e] = biases[(e / T_LEN) % NGROUPS];
}

__global__ __launch_bounds__(256, 4) void navar_main(
        const float* __restrict__ x,
        const float* __restrict__ w_in,  const float* __restrict__ b_in,
        const float* __restrict__ w_h,   const float* __restrict__ b_h,
        const float* __restrict__ w_out, const float* __restrict__ b_out,
        float* __restrict__ pred, float* __restrict__ contrib) {
    __shared__ float xs[BUF];
    __shared__ float hb[2][HIDDEN][BUF];   // ping-pong layer buffers, 32 KB

    const int p    = threadIdx.x;          // position within tile window
    const int tile = blockIdx.x % NTILES;
    const int sg   = blockIdx.x / NTILES;  // (batch, group) stream
    const int b    = sg / NGROUPS;
    const int g    = sg % NGROUPS;
    const int tg   = tile * TILE_OUT + p - HALO;   // global time

    // ---- stage x window (causal zero-pad at tg<0, clamp at end) ----
    float xv = 0.f;
    if (tg >= 0 && tg < T_LEN) xv = x[(size_t)(b * NGROUPS + g) * T_LEN + tg];
    xs[p] = xv;
    __syncthreads();

    // ---- input conv: 1 -> 16, dil 1, ReLU ----
    if (p >= 3) {
        const float t0 = xs[p-3], t1 = xs[p-2], t2 = xs[p-1], t3 = xs[p];
        const float* w  = w_in + g * HIDDEN * KSZ;   // block-uniform -> s_load
        const float* bb = b_in + g * HIDDEN;
        #pragma unroll
        for (int o = 0; o < HIDDEN; ++o) {
            float acc = bb[o];
            acc += w[o*4+0]*t0; acc += w[o*4+1]*t1;
            acc += w[o*4+2]*t2; acc += w[o*4+3]*t3;
            // per-layer causal padding: layer outputs at tg<0 are zeros
            hb[0][o][p] = (tg >= 0) ? fmaxf(acc, 0.f) : 0.f;
        }
    }
    __syncthreads();

    // ---- 3 dilated hidden blocks: 16 -> 16, dil 1,2,4, ReLU ----
    #pragma unroll
    for (int li = 0; li < 3; ++li) {
        const int d    = 1 << li;
        const int minP = (li == 0) ? 6 : (li == 1 ? 12 : 24);
        const float (*hs)[BUF] = hb[li & 1];
        float (*hd)[BUF]       = hb[(li & 1) ^ 1];
        if (p >= minP) {
            // preload all 64 taps into VGPRs (stride-1 LDS, conflict-free)
            float tp[HIDDEN][KSZ];
            #pragma unroll
            for (int i = 0; i < HIDDEN; ++i) {
                tp[i][0] = hs[i][p - 3*d];
                tp[i][1] = hs[i][p - 2*d];
                tp[i][2] = hs[i][p - 1*d];
                tp[i][3] = hs[i][p];
            }
            // weights block-uniform; contiguous 64 floats per output channel
            const float* w  = w_h + (size_t)(li * NGROUPS + g) * (HIDDEN * HIDDEN * KSZ);
            const float* bb = b_h + li * NGROUPS * HIDDEN + g * HIDDEN;
            #pragma unroll
            for (int o = 0; o < HIDDEN; ++o) {
                float acc = bb[o];
                const float* wo = w + o * (HIDDEN * KSZ);
                #pragma unroll
                for (int i = 0; i < HIDDEN; ++i) {
                    acc += wo[i*4+0]*tp[i][0];
                    acc += wo[i*4+1]*tp[i][1];
                    acc += wo[i*4+2]*tp[i][2];
                    acc += wo[i*4+3]*tp[i][3];
                }
                hd[o][p] = (tg >= 0) ? fmaxf(acc, 0.f) : 0.f;
            }
        }
        __syncthreads();
    }

    // ---- 1x1 output conv 16 -> 12, write contributions, atomic-accumulate prediction ----
    if (p >= HALO && tg < T_LEN) {     // p>=24 => tg>=0 automatically
        float h[HIDDEN];
        #pragma unroll
        for (int i = 0; i < HIDDEN; ++i) h[i] = hb[1][i][p];  // h3 lives in hb[1]
        const int gds  = g / NVAR;     // (dataset,sample) index 0..7
        const int srcv = g % NVAR;     // source variable
        const float* w  = w_out + g * NVAR * HIDDEN;
        const float* bb = b_out + g * NVAR;
        const size_t predBase = ((size_t)b * NGROUPS + gds * NVAR) * T_LEN + tg;
        const size_t conBase  = (((size_t)b * NGROUPS + gds * NVAR) * NVAR + srcv) * T_LEN + tg;
        #pragma unroll
        for (int v = 0; v < NVAR; ++v) {
            float acc = bb[v];
            #pragma unroll
            for (int i = 0; i < HIDDEN; ++i) acc += w[v*HIDDEN + i] * h[i];
            // contributions[b, d, s, dst=v, src=srcv, t]  (coalesced in t)
            contrib[conBase + (size_t)v * NVAR * T_LEN] = acc;
            // prediction[b, d, s, dst=v, t] += c  (sum over the 12 src groups)
            atomicAdd(pred + predBase + (size_t)v * T_LEN, acc);
        }
    }
}

extern "C" void kernel_launch(void* const* d_in, const int* in_sizes, int n_in,
                              void* d_out, int out_size, void* d_ws, size_t ws_size,
                              hipStream_t stream) {
    const float* x      = (const float*)d_in[0];
    const float* w_in   = (const float*)d_in[1];
    const float* b_in   = (const float*)d_in[2];
    const float* w_h    = (const float*)d_in[3];
    const float* b_h    = (const float*)d_in[4];
    const float* w_out  = (const float*)d_in[5];
    const float* b_out  = (const float*)d_in[6];
    const float* biases = (const float*)d_in[7];

    float* pred    = (float*)d_out;                               // 8*96*2048 floats
    float* contrib = pred + (size_t)BATCH * NGROUPS * T_LEN;      // 8*96*12*2048 floats

    // prediction init: exactly BATCH*NGROUPS*T_LEN / 256 = 6144 blocks
    navar_init_pred<<<(BATCH * NGROUPS * T_LEN) / 256, 256, 0, stream>>>(biases, pred);
    // main: one block per (batch, group, tile)
    navar_main<<<BATCH * NGROUPS * NTILES, 256, 0, stream>>>(
        x, w_in, b_in, w_h, b_h, w_out, b_out, pred, contrib);
}